// Round 7
// baseline (276.281 us; speedup 1.0000x reference)
//
#include <hip/hip_runtime.h>
#include <hip/hip_bf16.h>
#include <stdint.h>

#define M_DIM 8192
#define IN_F  4096
#define OUT_F 4096
#define NFP   256
#define NTI   64              // i8 K-tiles (4096/64)

typedef __attribute__((ext_vector_type(4)))  int   v4i;
typedef __attribute__((ext_vector_type(16))) int   v16i;
typedef __attribute__((ext_vector_type(16))) float v16f;
typedef __attribute__((ext_vector_type(8)))  short short8;

__device__ __forceinline__ void stage16(const void* g, void* l) {
    __builtin_amdgcn_global_load_lds(
        (const __attribute__((address_space(1))) int*)g,
        (__attribute__((address_space(3))) int*)l,
        16, 0, 0);
}

#define SB() __builtin_amdgcn_sched_barrier(0)

// ---------------------------------------------------------------------------
// Kernel 1: per-row quantization (unchanged from R6, verified).
// ---------------------------------------------------------------------------
__global__ __launch_bounds__(256)
void quant_rows(const float* __restrict__ x,
                const int* __restrict__ ind,
                char* __restrict__ qx,
                __hip_bfloat16* __restrict__ acts,
                float* __restrict__ xscale)
{
    __shared__ short omap[IN_F];
    __shared__ float red[4];
    __shared__ float s_xs;

    const int t = threadIdx.x;
    const int row = blockIdx.x;

    #pragma unroll
    for (int i = 0; i < IN_F / 256; ++i) omap[t + i * 256] = -1;
    __syncthreads();
    omap[ind[t]] = (short)t;
    __syncthreads();

    const float* xr = x + (size_t)row * IN_F + t * 16;
    float v[16];
    #pragma unroll
    for (int j = 0; j < 4; ++j) {
        float4 f = *(const float4*)(xr + j * 4);
        v[j*4+0] = f.x; v[j*4+1] = f.y; v[j*4+2] = f.z; v[j*4+3] = f.w;
    }
    short om[16];
    #pragma unroll
    for (int j = 0; j < 16; ++j) om[j] = omap[t * 16 + j];

    float m_nz = 0.f;
    #pragma unroll
    for (int j = 0; j < 16; ++j) {
        float a = fabsf(v[j]);
        if (om[j] < 0) m_nz = fmaxf(m_nz, a);
    }
    #pragma unroll
    for (int off = 32; off > 0; off >>= 1)
        m_nz = fmaxf(m_nz, __shfl_down(m_nz, off));
    if ((t & 63) == 0) red[t >> 6] = m_nz;
    __syncthreads();
    if (t == 0) {
        float a = fmaxf(fmaxf(red[0], red[1]), fmaxf(red[2], red[3]));
        xscale[row] = a / 127.0f;
        s_xs = (a > 0.f) ? (a / 127.0f) : 1.0f;
    }
    __syncthreads();
    const float xs = s_xs;

    union { char c[16]; int4 q; } u;
    #pragma unroll
    for (int j = 0; j < 16; ++j) {
        if (om[j] >= 0) {
            acts[(size_t)row * NFP + om[j]] = __float2bfloat16(v[j] / xs);
            u.c[j] = 0;
        } else {
            float r = rintf(v[j] / xs);               // half-to-even == jnp.round
            r = fminf(fmaxf(r, -128.f), 127.f);
            u.c[j] = (char)(int)r;
        }
    }
    *(int4*)(qx + (size_t)row * IN_F + t * 16) = u.q;
}

// ---------------------------------------------------------------------------
// Kernel 2: weight int32 -> int8 (exact) + outlier gather (unchanged).
// ---------------------------------------------------------------------------
__global__ __launch_bounds__(256)
void conv_w(const int* __restrict__ qw, const int* __restrict__ ind,
            char* __restrict__ qb, __hip_bfloat16* __restrict__ wob)
{
    const int n = blockIdx.x;
    const int t = threadIdx.x;
    const int* src = qw + (size_t)n * IN_F + t * 16;
    union { char c[16]; int4 q; } u;
    #pragma unroll
    for (int j = 0; j < 4; ++j) {
        int4 raw = *(const int4*)(src + j * 4);
        u.c[j*4+0] = (char)raw.x; u.c[j*4+1] = (char)raw.y;
        u.c[j*4+2] = (char)raw.z; u.c[j*4+3] = (char)raw.w;
    }
    *(int4*)(qb + (size_t)n * IN_F + t * 16) = u.q;
    wob[(size_t)n * NFP + t] = __float2bfloat16((float)qw[(size_t)n * IN_F + ind[t]]);
}

// ---------------------------------------------------------------------------
// Kernel 3: fused 256x256 GEMM, i8 main loop with m201-style FINE PHASES.
// Per K-tile: 2 phases, each {6 ds_read_b128 (one ks-slice); 2 stage16 (one
// half of tile t+2); s_barrier; lgkmcnt(0); setprio(1); 8 MFMA; setprio(0);
// s_barrier}; counted vmcnt(4) ONCE per tile (never 0 in-loop). 3 x 32KB
// LDS buffers, prefetch distance 2. Then bf16 outlier ext + epilogue (R6).
// ---------------------------------------------------------------------------
__global__ __launch_bounds__(512, 2)
void gemm_mix(const char* __restrict__ Aq, const char* __restrict__ Bq,
              const short* __restrict__ Ab, const short* __restrict__ Bb,
              const float* __restrict__ rscale,
              const float* __restrict__ cscale,
              const float* __restrict__ bias,
              float* __restrict__ out)
{
    __shared__ __attribute__((aligned(16))) char smem[98304];   // 3 x 32KB

    const int tid = threadIdx.x;
    const int wv = tid >> 6, lane = tid & 63;
    const int wm = wv >> 2, wn = wv & 3;
    const int l31 = lane & 31, kh = lane >> 5;

    // XCD-aware bijective swizzle (512 blocks, 512 % 8 == 0)
    const int bid = blockIdx.x;
    const int lin = (bid & 7) * 64 + (bid >> 3);
    const int bm = (lin & 31) * 256;
    const int bn = (lin >> 5) * 256;

    // i8 staging: 16KB half = 16 chunks of 1024B; wave stages chunks wv, wv+8.
    // chunk ca: hA=ca>>3 (row 0-127/128-255), g=(ca>>1)&3 (16B kgroup), rh=ca&1.
    auto stageA = [&](int t, int buf) {
        #pragma unroll
        for (int j = 0; j < 2; ++j) {
            const int ca = wv + j * 8;
            const int hA = ca >> 3, g = (ca >> 1) & 3, rh = ca & 1;
            const size_t grow = (size_t)(hA * 128 + rh * 64 + lane);
            stage16(Aq + (size_t)(bm + grow) * IN_F + t * 64 + g * 16,
                    smem + buf * 32768 + ca * 1024);
        }
    };
    auto stageB = [&](int t, int buf) {
        #pragma unroll
        for (int j = 0; j < 2; ++j) {
            const int ca = wv + j * 8;
            const int hA = ca >> 3, g = (ca >> 1) & 3, rh = ca & 1;
            const size_t grow = (size_t)(hA * 128 + rh * 64 + lane);
            stage16(Bq + (size_t)(bn + grow) * IN_F + t * 64 + g * 16,
                    smem + buf * 32768 + 16384 + ca * 1024);
        }
    };

    v16i acci[4][2] = {};

    // prologue: stage tiles 0,1; tile0 landed after vmcnt(4)
    stageA(0, 0); stageB(0, 0);
    stageA(1, 1); stageB(1, 1);
    SB();
    asm volatile("s_waitcnt vmcnt(4)" ::: "memory");
    __builtin_amdgcn_s_barrier();
    SB();

    for (int t = 0; t < NTI; ++t) {
        const int ct = t % 3;
        const int pf = (t + 2) % 3;
        const char* Abuf = smem + ct * 32768 + wm * 8192;
        const char* Bbuf = smem + ct * 32768 + 16384 + (wn >> 1) * 8192;
        const int coff = (wn & 1) * 64 * 16;

        // -------- phase 1 (ks = 0): reads + stage A(t+2) + 8 MFMA --------
        {
            v4i a[4], b[2];
            const int gk = kh * 2048;
            #pragma unroll
            for (int m = 0; m < 4; ++m)
                a[m] = *(const v4i*)(Abuf + gk + (m * 32 + l31) * 16);
            #pragma unroll
            for (int n = 0; n < 2; ++n)
                b[n] = *(const v4i*)(Bbuf + gk + coff + (n * 32 + l31) * 16);
            if (t + 2 < NTI) stageA(t + 2, pf);
            SB();
            __builtin_amdgcn_s_barrier();
            asm volatile("s_waitcnt lgkmcnt(0)" ::: "memory");
            SB();
            __builtin_amdgcn_s_setprio(1);
            #pragma unroll
            for (int m = 0; m < 4; ++m)
                #pragma unroll
                for (int n = 0; n < 2; ++n)
                    acci[m][n] = __builtin_amdgcn_mfma_i32_32x32x32_i8(
                        a[m], b[n], acci[m][n], 0, 0, 0);
            __builtin_amdgcn_s_setprio(0);
            SB();
            __builtin_amdgcn_s_barrier();
        }
        // -------- phase 2 (ks = 1): reads + stage B(t+2) + 8 MFMA + vmcnt --------
        {
            v4i a[4], b[2];
            const int gk = (2 + kh) * 2048;
            #pragma unroll
            for (int m = 0; m < 4; ++m)
                a[m] = *(const v4i*)(Abuf + gk + (m * 32 + l31) * 16);
            #pragma unroll
            for (int n = 0; n < 2; ++n)
                b[n] = *(const v4i*)(Bbuf + gk + coff + (n * 32 + l31) * 16);
            if (t + 2 < NTI) stageB(t + 2, pf);
            SB();
            __builtin_amdgcn_s_barrier();
            asm volatile("s_waitcnt lgkmcnt(0)" ::: "memory");
            SB();
            __builtin_amdgcn_s_setprio(1);
            #pragma unroll
            for (int m = 0; m < 4; ++m)
                #pragma unroll
                for (int n = 0; n < 2; ++n)
                    acci[m][n] = __builtin_amdgcn_mfma_i32_32x32x32_i8(
                        a[m], b[n], acci[m][n], 0, 0, 0);
            __builtin_amdgcn_s_setprio(0);
            SB();
            if (t < NTI - 2) asm volatile("s_waitcnt vmcnt(4)" ::: "memory");
            else             asm volatile("s_waitcnt vmcnt(0)" ::: "memory");
            __builtin_amdgcn_s_barrier();
        }
    }

    // convert exact i32 acc -> f32
    v16f accf[4][2];
    #pragma unroll
    for (int m = 0; m < 4; ++m)
        #pragma unroll
        for (int n = 0; n < 2; ++n)
            #pragma unroll
            for (int r = 0; r < 16; ++r)
                accf[m][n][r] = (float)acci[m][n][r];

    // ---- bf16 outlier tiles (K = 256 = 4 x 64), single-buffered (R6) ----
    for (int to = 0; to < 4; ++to) {
        #pragma unroll
        for (int j = 0; j < 4; ++j) {
            const int ca = wv * 4 + j;
            const int hA = ca >> 4, g = (ca >> 1) & 7, rh = ca & 1;
            const size_t grow = (size_t)(hA * 128 + rh * 64 + lane);
            const int gcolb = to * 128 + g * 16;
            stage16((const char*)Ab + (size_t)(bm + grow) * (NFP * 2) + gcolb,
                    smem + ca * 1024);
            stage16((const char*)Bb + (size_t)(bn + grow) * (NFP * 2) + gcolb,
                    smem + 32768 + ca * 1024);
        }
        SB();
        asm volatile("s_waitcnt vmcnt(0)" ::: "memory");
        __builtin_amdgcn_s_barrier();
        SB();

        const char* Abuf = smem + wm * 16384;
        const char* Bbuf = smem + 32768 + (wn >> 1) * 16384;
        const int coff = (wn & 1) * 64 * 16;
        #pragma unroll
        for (int ks = 0; ks < 4; ++ks) {
            short8 a[4], b[2];
            const int gk = (ks * 2 + kh) * 2048;
            #pragma unroll
            for (int m = 0; m < 4; ++m)
                a[m] = *(const short8*)(Abuf + gk + (m * 32 + l31) * 16);
            #pragma unroll
            for (int n = 0; n < 2; ++n)
                b[n] = *(const short8*)(Bbuf + gk + coff + (n * 32 + l31) * 16);
            __builtin_amdgcn_s_setprio(1);
            #pragma unroll
            for (int m = 0; m < 4; ++m)
                #pragma unroll
                for (int n = 0; n < 2; ++n)
                    accf[m][n] = __builtin_amdgcn_mfma_f32_32x32x16_bf16(
                        a[m], b[n], accf[m][n], 0, 0, 0);
            __builtin_amdgcn_s_setprio(0);
        }
        SB();
        asm volatile("s_waitcnt lgkmcnt(0)" ::: "memory");
        __builtin_amdgcn_s_barrier();
        SB();
    }

    // epilogue: 32x32 C/D layout col=lane&31, row=(r&3)+8*(r>>2)+4*(lane>>5)
    float csv[2], biv[2];
    int colv[2];
    #pragma unroll
    for (int n = 0; n < 2; ++n) {
        colv[n] = bn + wn * 64 + n * 32 + l31;
        csv[n] = cscale[colv[n]];
        biv[n] = bias[colv[n]];
    }
    #pragma unroll
    for (int m = 0; m < 4; ++m) {
        #pragma unroll
        for (int r = 0; r < 16; ++r) {
            const int row = bm + wm * 128 + m * 32 + (r & 3) + 8 * (r >> 2) + 4 * kh;
            const float rs = rscale[row];
            #pragma unroll
            for (int n = 0; n < 2; ++n)
                out[(size_t)row * OUT_F + colv[n]] =
                    accf[m][n][r] * rs * csv[n] + biv[n];
        }
    }
}

// ---------------------------------------------------------------------------
extern "C" void kernel_launch(void* const* d_in, const int* in_sizes, int n_in,
                              void* d_out, int out_size, void* d_ws, size_t ws_size,
                              hipStream_t stream)
{
    const float* x         = (const float*)d_in[0];
    const int*   q_weight  = (const int*)d_in[1];    // int32 on device
    const float* scale_col = (const float*)d_in[2];
    const float* bias      = (const float*)d_in[3];
    const int*   ind       = (const int*)d_in[4];
    float*       out       = (float*)d_out;

    // workspace (~57 MB)
    char*           qx   = (char*)d_ws;                              // M x IN_F i8
    char*           qb   = qx + (size_t)M_DIM * IN_F;                // OUT_F x IN_F i8
    __hip_bfloat16* acts = (__hip_bfloat16*)(qb + (size_t)OUT_F * IN_F);  // M x NFP
    __hip_bfloat16* wob  = acts + (size_t)M_DIM * NFP;               // OUT_F x NFP
    float*          xs   = (float*)(wob + (size_t)OUT_F * NFP);      // M

    const size_t need = (size_t)((char*)(xs + M_DIM) - (char*)d_ws);
    if (ws_size < need) return;

    quant_rows<<<dim3(M_DIM), dim3(256), 0, stream>>>(x, ind, qx, acts, xs);
    conv_w<<<dim3(OUT_F), dim3(256), 0, stream>>>(q_weight, ind, qb, wob);

    gemm_mix<<<dim3((M_DIM / 256) * (OUT_F / 256)), dim3(512), 0, stream>>>(
        qx, qb, (const short*)acts, (const short*)wob,
        xs, scale_col, bias, out);
}